// Round 1
// baseline (391.396 us; speedup 1.0000x reference)
//
#include <hip/hip_runtime.h>

// Affinity propagation, 3 axes × 3 iterations on a [X=256, Y=256, Z=32] fp32 volume.
// guidance: [24, X, Y, Z]; blur/out: [X, Y, Z] (B==1).
//
// Per step (direction DIR), per voxel v:
//   g_k  = guidance[DIR*8+k][v + off_k]   (0 if off-grid in the stencil plane)
//   asum = sum_k |g_k|
//   out[v] = r[v] + (sum_k g_k * r[v+off_k] - (sum_k g_k) * r[v]) / asum
//
// Channel k -> (d1,d2): (1,1),(1,0),(1,-1),(0,1),(0,-1),(-1,1),(-1,0),(-1,-1)
//   DIR 0: (d1,d2) applied to (x,y);  DIR 1: (x,z);  DIR 2: (y,z)

constexpr int X = 256, Y = 256, Z = 32;
constexpr int NV = X * Y * Z;

template <int DIR>
__global__ __launch_bounds__(256) void prop_step(const float* __restrict__ g,
                                                 const float* __restrict__ rin,
                                                 float* __restrict__ rout) {
    const int tid = blockIdx.x * 256 + threadIdx.x;
    const int z = tid & (Z - 1);
    const int y = (tid >> 5) & (Y - 1);
    const int x = tid >> 13;

    const int d1[8] = {1, 1, 1, 0, 0, -1, -1, -1};
    const int d2[8] = {1, 0, -1, 1, -1, 1, 0, -1};

    const float rc = rin[tid];
    const float* gc = g + DIR * 8 * NV;

    float asum = 0.f, gs = 0.f, acc = 0.f;
#pragma unroll
    for (int k = 0; k < 8; ++k) {
        int a, b, nofs;
        if (DIR == 0)      { a = x + d1[k]; b = y + d2[k]; nofs = d1[k] * (Y * Z) + d2[k] * Z; }
        else if (DIR == 1) { a = x + d1[k]; b = z + d2[k]; nofs = d1[k] * (Y * Z) + d2[k]; }
        else               { a = y + d1[k]; b = z + d2[k]; nofs = d1[k] * Z + d2[k]; }
        const int lim1 = (DIR == 2) ? Y : X;
        const int lim2 = (DIR == 0) ? Y : Z;
        if (a >= 0 && a < lim1 && b >= 0 && b < lim2) {
            const float gv = gc[k * NV + tid + nofs];
            const float rv = rin[tid + nofs];
            asum += fabsf(gv);
            gs += gv;
            acc = fmaf(gv, rv, acc);
        }
    }
    rout[tid] = rc + (acc - gs * rc) / asum;
}

extern "C" void kernel_launch(void* const* d_in, const int* in_sizes, int n_in,
                              void* d_out, int out_size, void* d_ws, size_t ws_size,
                              hipStream_t stream) {
    const float* g    = (const float*)d_in[0];
    const float* blur = (const float*)d_in[1];
    float* out = (float*)d_out;
    float* ws  = (float*)d_ws;   // needs NV*4 = 8 MiB

    const dim3 grid(NV / 256), block(256);

    // 9 steps, ping-pong: blur -> out -> ws -> out -> ... ; step 8 (even) -> out.
    const float* src = blur;
    int step = 0;
    for (int it = 0; it < 3; ++it) {
        for (int dir = 0; dir < 3; ++dir) {
            float* dst = (step & 1) ? ws : out;
            switch (dir) {
                case 0: prop_step<0><<<grid, block, 0, stream>>>(g, src, dst); break;
                case 1: prop_step<1><<<grid, block, 0, stream>>>(g, src, dst); break;
                case 2: prop_step<2><<<grid, block, 0, stream>>>(g, src, dst); break;
            }
            src = dst;
            ++step;
        }
    }
}

// Round 2
// 375.298 us; speedup vs baseline: 1.0429x; 1.0429x over previous
//
#include <hip/hip_runtime.h>

// Affinity propagation, 3 axes × 3 iterations on [X=256, Y=256, Z=32] fp32.
// guidance: [24, X, Y, Z]; blur/out: [X, Y, Z].
//
// Per step (direction DIR), per voxel v:
//   g_k  = guidance[DIR*8+k][v + off_k]   (0 if off-grid in the stencil plane)
//   asum = sum_k |g_k| ; out[v] = r[v] + (sum_k g_k*r[v+off_k] - (sum_k g_k)*r[v]) / asum
//
// k -> (d1,d2): (1,1),(1,0),(1,-1),(0,1),(0,-1),(-1,1),(-1,0),(-1,-1)
//   DIR 0: (d1,d2)->(x,y)   DIR 1: (x,z)   DIR 2: (y,z)
//
// R1: 4 voxels (z) per thread, float4 loads; z+-1 shifts via aligned float4 +
// guarded edge scalar, in-register shuffle. OOB neighbors -> guidance masked
// to 0 (kills asum/gsum/acc contribution == reference zero-pad).

constexpr int X = 256, Y = 256, Z = 32;
constexpr int NV = X * Y * Z;
constexpr int YZ = Y * Z;

__device__ __forceinline__ float4 zero4() { return make_float4(0.f, 0.f, 0.f, 0.f); }

__device__ __forceinline__ void accum(const float4 gk, const float4 rk,
                                      float* asum, float* gsum, float* acc) {
    asum[0] += fabsf(gk.x); gsum[0] += gk.x; acc[0] = fmaf(gk.x, rk.x, acc[0]);
    asum[1] += fabsf(gk.y); gsum[1] += gk.y; acc[1] = fmaf(gk.y, rk.y, acc[1]);
    asum[2] += fabsf(gk.z); gsum[2] += gk.z; acc[2] = fmaf(gk.z, rk.z, acc[2]);
    asum[3] += fabsf(gk.w); gsum[3] += gk.w; acc[3] = fmaf(gk.w, rk.w, acc[3]);
}

template <int DIR>
__global__ __launch_bounds__(256) void prop4(const float* __restrict__ g,
                                             const float* __restrict__ rin,
                                             float* __restrict__ rout) {
    const int t  = blockIdx.x * 256 + threadIdx.x;
    const int f0 = t << 2;                 // first of 4 consecutive z voxels
    const int z  = f0 & (Z - 1);           // multiple of 4
    const int y  = (f0 >> 5) & (Y - 1);
    const int x  = f0 >> 13;

    constexpr int d1[8] = {1, 1, 1, 0, 0, -1, -1, -1};
    constexpr int d2[8] = {1, 0, -1, 1, -1, 1, 0, -1};

    const float* gc = g + DIR * 8 * NV;
    const float4 rc = *(const float4*)(rin + f0);
    float asum[4] = {0, 0, 0, 0}, gsum[4] = {0, 0, 0, 0}, acc[4] = {0, 0, 0, 0};

    if (DIR == 0) {
        // d1->x (stride YZ), d2->y (stride Z): every access float4-aligned.
#pragma unroll
        for (int k = 0; k < 8; ++k) {
            const int a = x + d1[k], b = y + d2[k];
            if (a >= 0 && a < X && b >= 0 && b < Y) {
                const int ofs = f0 + d1[k] * YZ + d2[k] * Z;
                const float4 gv = *(const float4*)(gc + k * NV + ofs);
                const float4 rv = *(const float4*)(rin + ofs);
                accum(gv, rv, asum, gsum, acc);
            }
        }
    } else {
        // d1 -> x (DIR1, stride YZ) or y (DIR2, stride Z); d2 -> z (stride 1).
        const int s1 = (DIR == 1) ? YZ : Z;
        const int c1 = (DIR == 1) ? x : y;

        // Three r rows (d1 = +1, 0, -1), each a 6-float window [z-1, z+4].
        float4 rv[3]; float rl[3], rr[3];
#pragma unroll
        for (int j = 0; j < 3; ++j) {
            const int dd = 1 - j;          // +1, 0, -1
            const bool v = (c1 + dd >= 0) && (c1 + dd < 256);
            const float* p = rin + f0 + dd * s1;
            rv[j] = v ? *(const float4*)p : zero4();
            rl[j] = (v && z > 0)     ? p[-1] : 0.f;
            rr[j] = (v && z < Z - 4) ? p[4]  : 0.f;
        }

#pragma unroll
        for (int k = 0; k < 8; ++k) {
            const int j = 1 - d1[k];
            const bool v = (c1 + d1[k] >= 0) && (c1 + d1[k] < 256);
            const float* p = gc + k * NV + f0 + d1[k] * s1;
            const float4 gv = v ? *(const float4*)p : zero4();
            float4 gk, rk;
            if (d2[k] == 1) {
                const float s = (v && z < Z - 4) ? p[4] : 0.f;
                gk = make_float4(gv.y, gv.z, gv.w, s);
                rk = make_float4(rv[j].y, rv[j].z, rv[j].w, rr[j]);
            } else if (d2[k] == -1) {
                const float s = (v && z > 0) ? p[-1] : 0.f;
                gk = make_float4(s, gv.x, gv.y, gv.z);
                rk = make_float4(rl[j], rv[j].x, rv[j].y, rv[j].z);
            } else {
                gk = gv; rk = rv[j];
            }
            accum(gk, rk, asum, gsum, acc);
        }
    }

    float4 o;
    o.x = rc.x + (acc[0] - gsum[0] * rc.x) / asum[0];
    o.y = rc.y + (acc[1] - gsum[1] * rc.y) / asum[1];
    o.z = rc.z + (acc[2] - gsum[2] * rc.z) / asum[2];
    o.w = rc.w + (acc[3] - gsum[3] * rc.w) / asum[3];
    *(float4*)(rout + f0) = o;
}

extern "C" void kernel_launch(void* const* d_in, const int* in_sizes, int n_in,
                              void* d_out, int out_size, void* d_ws, size_t ws_size,
                              hipStream_t stream) {
    const float* g    = (const float*)d_in[0];
    const float* blur = (const float*)d_in[1];
    float* out = (float*)d_out;
    float* ws  = (float*)d_ws;   // needs NV*4 = 8 MiB

    const dim3 grid(NV / 1024), block(256);

    // 9 steps, ping-pong: blur -> out -> ws -> out -> ... ; step 8 (even) -> out.
    const float* src = blur;
    int step = 0;
    for (int it = 0; it < 3; ++it) {
        for (int dir = 0; dir < 3; ++dir) {
            float* dst = (step & 1) ? ws : out;
            switch (dir) {
                case 0: prop4<0><<<grid, block, 0, stream>>>(g, src, dst); break;
                case 1: prop4<1><<<grid, block, 0, stream>>>(g, src, dst); break;
                case 2: prop4<2><<<grid, block, 0, stream>>>(g, src, dst); break;
            }
            src = dst;
            ++step;
        }
    }
}